// Round 2
// baseline (230.785 us; speedup 1.0000x reference)
//
#include <hip/hip_runtime.h>

// T=8, L=2e6, B=16384. Outputs (flat f32 concat): [0] indices 16M, [1] offsets 131073, [2] weights 16M.
constexpr long NA = 16000000;   // T*L
constexpr long NB = 131073;     // T*B+1
constexpr int  BLK = 256;
constexpr int  UNR = 4;                                   // 16B chunks per thread
constexpr int  CHUNKS = 4000000;                          // 16B chunks per big region (16M elems * 4B / 16B)
constexpr int  GA = (CHUNKS + BLK * UNR - 1) / (BLK * UNR);  // 3907 blocks (indices)
constexpr int  GC = GA;                                      // 3907 blocks (weights)
constexpr int  GB = ((int)NB + BLK - 1) / BLK;               // 513 blocks (offsets)

// clang vector types.
typedef int   v4i   __attribute__((ext_vector_type(4)));
typedef float v4f   __attribute__((ext_vector_type(4)));
// 16-byte store with only 4-byte alignment: global_store_dwordx4 needs only dword
// alignment, so one instruction covers the out-region misaligned by 1 float.
typedef float v4f_u __attribute__((ext_vector_type(4), aligned(4)));

__global__ __launch_bounds__(BLK) void tbe_prep(
    const int* __restrict__ indices,
    const int* __restrict__ offsets,
    const float* __restrict__ weights,
    float* __restrict__ out) {
  const int bid = blockIdx.x;
  const int tid = threadIdx.x;

  if (bid < GA) {
    // ---- Output 0: indices int32 -> f32 (exact), fully 16B-aligned both sides ----
    const v4i* p = (const v4i*)indices;
    v4f* o = (v4f*)out;
    const int base = bid * (BLK * UNR) + tid;
    if (base + (UNR - 1) * BLK < CHUNKS) {
      // Hot path: no per-lane predication. Plain (cached) loads — the 6.3 TB/s
      // copy ceiling was measured with plain loads; nt loads read slower.
      v4i a[UNR];
#pragma unroll
      for (int u = 0; u < UNR; ++u) a[u] = p[base + u * BLK];
#pragma unroll
      for (int u = 0; u < UNR; ++u) {
        v4f r;
        r.x = (float)a[u].x; r.y = (float)a[u].y;
        r.z = (float)a[u].z; r.w = (float)a[u].w;
        __builtin_nontemporal_store(r, &o[base + u * BLK]);  // write-once: keep NT
      }
    } else {
      for (int u = 0; u < UNR; ++u) {
        int c = base + u * BLK;
        if (c < CHUNKS) {
          v4i a = p[c];
          v4f r;
          r.x = (float)a.x; r.y = (float)a.y;
          r.z = (float)a.z; r.w = (float)a.w;
          __builtin_nontemporal_store(r, &o[c]);
        }
      }
    }
  } else if (bid < GA + GC) {
    // ---- Output 2: weights f32 copy; out region starts at element NA+NB (== 1 mod 4) ----
    const v4f* p = (const v4f*)weights;
    v4f_u* o = (v4f_u*)(out + (NA + NB));   // 4B-aligned 16B stores
    const int base = (bid - GA) * (BLK * UNR) + tid;
    if (base + (UNR - 1) * BLK < CHUNKS) {
      v4f a[UNR];
#pragma unroll
      for (int u = 0; u < UNR; ++u) a[u] = p[base + u * BLK];
#pragma unroll
      for (int u = 0; u < UNR; ++u)
        __builtin_nontemporal_store(a[u], &o[base + u * BLK]);
    } else {
      for (int u = 0; u < UNR; ++u) {
        int c = base + u * BLK;
        if (c < CHUNKS) {
          v4f a = p[c];
          __builtin_nontemporal_store(a, &o[c]);
        }
      }
    }
  } else {
    // ---- Output 1: combined_offsets, scalar (131,073 elements, negligible) ----
    long j = (long)(bid - GA - GC) * BLK + tid;
    if (j < NB) {
      int v;
      if (j == NB - 1) {
        v = 16000000;                            // T*L sentinel
      } else {
        int t = (int)(j >> 14);                  // j / B
        int k = (int)(j & 16383);                // j % B
        v = offsets[t * 16385 + k] + t * 2000000;
      }
      out[NA + j] = (float)v;
    }
  }
}

extern "C" void kernel_launch(void* const* d_in, const int* in_sizes, int n_in,
                              void* d_out, int out_size, void* d_ws, size_t ws_size,
                              hipStream_t stream) {
  const int*   indices = (const int*)d_in[0];
  const int*   offsets = (const int*)d_in[1];
  const float* weights = (const float*)d_in[2];
  float*       out     = (float*)d_out;

  const int grid = GA + GC + GB;  // 8,327 blocks
  tbe_prep<<<dim3(grid), dim3(BLK), 0, stream>>>(indices, offsets, weights, out);
}

// Round 5
// 216.298 us; speedup vs baseline: 1.0670x; 1.0670x over previous
//
#include <hip/hip_runtime.h>

// T=8, L=2e6, B=16384. Outputs (flat f32 concat): [0] indices 16M, [1] offsets 131073, [2] weights 16M.
constexpr long NA = 16000000;   // T*L
constexpr long NB = 131073;     // T*B+1
constexpr long WOFF = NA + NB;  // weights out start, element 16,131,073 (== 1 mod 4)
constexpr int  BLK = 256;
constexpr int  UNR = 4;                                   // 16B chunks per thread
constexpr int  CHUNKS = 4000000;                          // 16B chunks, indices region
constexpr int  CHW    = 3999999;                          // 16B chunks, weights main (after 3-elem prologue)
constexpr int  GA = (CHUNKS + BLK * UNR - 1) / (BLK * UNR);  // 3907 blocks (indices)
constexpr int  GC = (CHW    + BLK * UNR - 1) / (BLK * UNR);  // 3907 blocks (weights)
constexpr int  GB = ((int)NB + BLK - 1) / BLK;               // 513 blocks (offsets)

// clang vector types: accepted by __builtin_nontemporal_load/store.
typedef int   v4i   __attribute__((ext_vector_type(4)));
typedef float v4f   __attribute__((ext_vector_type(4)));
// 16B access with only 4B alignment (dwordx4 needs only dword alignment).
typedef float v4f_u __attribute__((ext_vector_type(4), aligned(4)));

__global__ __launch_bounds__(BLK) void tbe_prep(
    const int* __restrict__ indices,
    const int* __restrict__ offsets,
    const float* __restrict__ weights,
    float* __restrict__ out) {
  const int bid = blockIdx.x;
  const int tid = threadIdx.x;

  if (bid < GA) {
    // ---- Output 0: indices int32 -> f32 (exact), 16B-aligned both sides ----
    // NT loads: measured faster than cached loads here (R0 64us vs R1 77us) —
    // read-allocate churn in TCC costs more than the L3 hits save.
    const v4i* p = (const v4i*)indices;
    v4f* o = (v4f*)out;
    const int base = bid * (BLK * UNR) + tid;
    if (base + (UNR - 1) * BLK < CHUNKS) {
      v4i a[UNR];
#pragma unroll
      for (int u = 0; u < UNR; ++u)
        a[u] = __builtin_nontemporal_load(&p[base + u * BLK]);
#pragma unroll
      for (int u = 0; u < UNR; ++u) {
        v4f r;
        r.x = (float)a[u].x; r.y = (float)a[u].y;
        r.z = (float)a[u].z; r.w = (float)a[u].w;
        __builtin_nontemporal_store(r, &o[base + u * BLK]);
      }
    } else {
      for (int u = 0; u < UNR; ++u) {
        int c = base + u * BLK;
        if (c < CHUNKS) {
          v4i a = __builtin_nontemporal_load(&p[c]);
          v4f r;
          r.x = (float)a.x; r.y = (float)a.y;
          r.z = (float)a.z; r.w = (float)a.w;
          __builtin_nontemporal_store(r, &o[c]);
        }
      }
    }
  } else if (bid < GA + GC) {
    // ---- Output 2: weights copy. Misalignment moved to the LOAD side: ----
    // elements 0..2 and 15,999,999 are done in the offsets block; here chunk c
    // covers weights[3+4c .. 6+4c] (load misaligned by 12B, no RMW penalty)
    // into out[WOFF+3+4c ..] (store fully 16B-aligned, no partial-line RMW).
    const v4f_u* p = (const v4f_u*)(weights + 3);
    v4f* o = (v4f*)(out + (WOFF + 3));
    const int base = (bid - GA) * (BLK * UNR) + tid;
    if (base + (UNR - 1) * BLK < CHW) {
      v4f a[UNR];
#pragma unroll
      for (int u = 0; u < UNR; ++u)
        a[u] = __builtin_nontemporal_load(&p[base + u * BLK]);
#pragma unroll
      for (int u = 0; u < UNR; ++u)
        __builtin_nontemporal_store(a[u], &o[base + u * BLK]);
    } else {
      for (int u = 0; u < UNR; ++u) {
        int c = base + u * BLK;
        if (c < CHW) {
          v4f a = __builtin_nontemporal_load(&p[c]);
          __builtin_nontemporal_store(a, &o[c]);
        }
      }
    }
  } else {
    // ---- Output 1: combined_offsets (131,073 elems) + weights prologue/epilogue ----
    long j = (long)(bid - GA - GC) * BLK + tid;
    if (j < NB) {
      int v;
      if (j == NB - 1) {
        v = 16000000;                            // T*L sentinel
      } else {
        int t = (int)(j >> 14);                  // j / B
        int k = (int)(j & 16383);                // j % B
        v = offsets[t * 16385 + k] + t * 2000000;
      }
      out[NA + j] = (float)v;
    }
    if (bid == GA + GC) {
      if (tid < 3)   out[WOFF + tid] = weights[tid];                 // prologue: 3 elems
      if (tid == 3)  out[WOFF + 15999999] = weights[15999999];       // epilogue: 1 elem
    }
  }
}

extern "C" void kernel_launch(void* const* d_in, const int* in_sizes, int n_in,
                              void* d_out, int out_size, void* d_ws, size_t ws_size,
                              hipStream_t stream) {
  const int*   indices = (const int*)d_in[0];
  const int*   offsets = (const int*)d_in[1];
  const float* weights = (const float*)d_in[2];
  float*       out     = (float*)d_out;

  const int grid = GA + GC + GB;  // 8,327 blocks
  tbe_prep<<<dim3(grid), dim3(BLK), 0, stream>>>(indices, offsets, weights, out);
}